// Round 4
// baseline (477.155 us; speedup 1.0000x reference)
//
#include <hip/hip_runtime.h>
#include <hip/hip_bf16.h>

#define NN 32
#define CC 256
#define HH 56
#define WW 56
#define HP 58
#define BN_EPS 1e-5f

using f32x4  = __attribute__((ext_vector_type(4))) float;
using short8 = __attribute__((ext_vector_type(8))) short;

__device__ __forceinline__ void gload16(const void* g, void* l) {
    __builtin_amdgcn_global_load_lds(
        (const __attribute__((address_space(1))) void*)g,
        (__attribute__((address_space(3))) void*)l, 16, 0, 0);
}

// ---------------- layout transforms ----------------

// x NCHW fp32 -> xt padded NHWC bf16 [N][58][58][256]
__global__ __launch_bounds__(256) void transform_x(const float* __restrict__ x,
                                                   __hip_bfloat16* __restrict__ xt) {
    __shared__ float t[64][65];
    const int tx = threadIdx.x & 63, ty = threadIdx.x >> 6;
    const int c0 = blockIdx.x * 64, h = blockIdx.y, n = blockIdx.z;
    #pragma unroll
    for (int i = 0; i < 16; ++i) {
        const int c = ty + i * 4;
        float v = 0.f;
        if (tx < WW) v = x[(((size_t)n * CC + c0 + c) * HH + h) * WW + tx];
        t[c][tx] = v;
    }
    __syncthreads();
    #pragma unroll
    for (int i = 0; i < 16; ++i) {
        const int w = ty + i * 4;
        if (w < WW)
            xt[((n * HP + h + 1) * HP + (w + 1)) * CC + c0 + tx] = __float2bfloat16(t[tx][w]);
    }
}

// w [co][ci][3][3] fp32 -> wt [tap][co][ci] bf16
__global__ void transform_w(const float* __restrict__ w, __hip_bfloat16* __restrict__ wt) {
    const int co = blockIdx.x, tap = blockIdx.y, ci = threadIdx.x;
    wt[(tap * CC + co) * CC + ci] = __float2bfloat16(w[(co * CC + ci) * 9 + tap]);
}

// zero spatial border of a padded NHWC buffer
__global__ void zero_borders(__hip_bfloat16* __restrict__ buf) {
    const int i = blockIdx.x, n = blockIdx.y;
    int h, w;
    if (i < 58)       { h = 0;              w = i; }
    else if (i < 116) { h = 57;             w = i - 58; }
    else if (i < 172) { h = 1 + (i - 116);  w = 0; }
    else              { h = 1 + (i - 172);  w = 57; }
    buf[((n * HP + h) * HP + w) * CC + threadIdx.x] = __float2bfloat16(0.f);
}

// ---------------- implicit-GEMM conv3x3 + BN (+identity) + ReLU ----------------
// act: padded NHWC bf16 [N][58][58][256]; wt: [9][co=256][ci=256] bf16
// Block 256 thr = 4 waves (2x2), tile BM=128 pixels x BN=128 co, BK=64.
// 2-phase prefetch (double-buffered LDS), T2 XOR-swizzle via pre-swizzled
// global source + swizzled ds_read (LDS dest stays linear for global_load_lds).
// K-order: ci-chunk OUTER, tap INNER (tap re-reads hit L2).
template<bool SECOND>
__global__ __launch_bounds__(256) void conv_mfma(
    const __hip_bfloat16* __restrict__ act,
    const __hip_bfloat16* __restrict__ wt,
    const float* __restrict__ g, const float* __restrict__ bb,
    const float* __restrict__ rm, const float* __restrict__ rv,
    const float* __restrict__ identity,
    void* __restrict__ out)
{
    __shared__ short As[2][128 * 64];   // [buf][pixel-row][k] 16 KB each
    __shared__ short Bs[2][128 * 64];   // [buf][co-row][k]

    const int tid  = threadIdx.x;
    const int lane = tid & 63;
    const int wid  = tid >> 6;
    const int wm = wid >> 1, wn = wid & 1;

    // XCD swizzle: logical tiles 0..199 -> XCD0, 200..399 -> XCD1, ...
    const int bid     = blockIdx.x;
    const int logical = (bid & 7) * 200 + (bid >> 3);
    const int nb   = logical & 1;        // co-half (adjacent logical ids share A)
    const int rest = logical >> 1;       // (n*25 + mb): consecutive = adjacent pixels
    const int mb   = rest % 25;
    const int n    = rest / 25;

    // Swizzled per-lane source column (involution: col16 ^= row&7, row&7 == lane>>3)
    const int scol = (lane & 7) ^ (lane >> 3);   // 16B-slot index 0..7

    // per-lane staging base byte-offsets (row geometry fixed across K-loop)
    int abase[4], bbase[4];
    #pragma unroll
    for (int j = 0; j < 4; ++j) {
        const int r = wid * 32 + j * 8 + (lane >> 3);
        int p = mb * 128 + r;
        if (p > HH * WW - 1) p = HH * WW - 1;          // clamp padded-M garbage rows
        const int h = p / WW, w = p - h * WW;
        abase[j] = (((n * HP + h) * HP + w) * CC + scol * 8) * 2;
        const int co = nb * 128 + r;
        bbase[j] = (co * CC + scol * 8) * 2;
    }

    f32x4 acc[4][4];
    #pragma unroll
    for (int i = 0; i < 4; ++i)
        #pragma unroll
        for (int j = 0; j < 4; ++j)
            acc[i][j] = (f32x4){0.f, 0.f, 0.f, 0.f};

    const char* actB = (const char*)act;
    const char* wtB  = (const char*)wt;
    char* AsL = (char*)As;
    char* BsL = (char*)Bs;

    // K-step t in [0,36): cic = t/9 (64-ci chunk), tap = t%9
    auto stage = [&](int buf, int t) {
        const int cic = t / 9;
        const int tap = t - cic * 9;
        const int dh = tap / 3, dw = tap - dh * 3;
        const int aoff = (dh * HP + dw) * CC * 2 + cic * 128;
        const int boff = tap * (CC * CC * 2) + cic * 128;
        #pragma unroll
        for (int j = 0; j < 4; ++j) {
            gload16(actB + abase[j] + aoff, AsL + buf * 16384 + wid * 4096 + j * 1024);
            gload16(wtB  + bbase[j] + boff, BsL + buf * 16384 + wid * 4096 + j * 1024);
        }
    };

    const int rlane = lane & 15;
    const int xorb  = (lane & 7) << 4;            // read-side swizzle (row&7 == lane&7)
    const int colb  = (lane >> 4) << 4;

    auto compute = [&](int buf) {
        #pragma unroll
        for (int ks = 0; ks < 2; ++ks) {
            const int coladdr = (ks * 64 + colb) ^ xorb;
            short8 a[4], bq[4];
            #pragma unroll
            for (int mf = 0; mf < 4; ++mf)
                a[mf] = *(const short8*)(AsL + buf * 16384
                            + (wm * 64 + mf * 16 + rlane) * 128 + coladdr);
            #pragma unroll
            for (int nf = 0; nf < 4; ++nf)
                bq[nf] = *(const short8*)(BsL + buf * 16384
                            + (wn * 64 + nf * 16 + rlane) * 128 + coladdr);
            #pragma unroll
            for (int mf = 0; mf < 4; ++mf)
                #pragma unroll
                for (int nf = 0; nf < 4; ++nf)
                    acc[mf][nf] = __builtin_amdgcn_mfma_f32_16x16x32_bf16(
                        a[mf], bq[nf], acc[mf][nf], 0, 0, 0);
        }
    };

    // prologue
    stage(0, 0);
    __syncthreads();                     // implicit vmcnt(0) drain: tile 0 ready
    // main loop: issue next stage BEFORE compute; one barrier per K-step
    for (int t = 0; t < 35; ++t) {
        stage((t + 1) & 1, t + 1);       // prefetch next tile into other buffer
        compute(t & 1);                  // MFMA on current tile
        __syncthreads();                 // drains vmcnt (stage done) + orders buffers
    }
    compute(1);                          // t = 35

    // epilogue: BN (+identity) + ReLU
    const int lm = lane >> 4, ln = lane & 15;
    #pragma unroll
    for (int nf = 0; nf < 4; ++nf) {
        const int co = nb * 128 + wn * 64 + nf * 16 + ln;
        const float scale = g[co] * rsqrtf(rv[co] + BN_EPS);
        const float bias  = bb[co] - rm[co] * scale;
        #pragma unroll
        for (int mf = 0; mf < 4; ++mf) {
            const int p0 = mb * 128 + wm * 64 + mf * 16 + lm * 4;
            if (p0 >= HH * WW) continue;     // padded-M garbage rows
            f32x4 v = acc[mf][nf];
            if (SECOND) {
                const size_t off = (size_t)(n * CC + co) * (HH * WW) + p0;
                const float4 id = *(const float4*)(identity + off);
                float4 o;
                o.x = fmaxf(fmaf(v[0], scale, bias) + id.x, 0.f);
                o.y = fmaxf(fmaf(v[1], scale, bias) + id.y, 0.f);
                o.z = fmaxf(fmaf(v[2], scale, bias) + id.z, 0.f);
                o.w = fmaxf(fmaf(v[3], scale, bias) + id.w, 0.f);
                *(float4*)((float*)out + off) = o;
            } else {
                const int h = p0 / WW, w = p0 - h * WW;   // 4 pixels never cross a row (56%4==0)
                __hip_bfloat16* yp = (__hip_bfloat16*)out
                    + ((n * HP + h + 1) * HP + (w + 1)) * CC + co;
                #pragma unroll
                for (int r = 0; r < 4; ++r)
                    yp[r * CC] = __float2bfloat16(fmaxf(fmaf(v[r], scale, bias), 0.f));
            }
        }
    }
}

// ---------------- round-1 naive fallback (used only if ws too small) ----------------
__device__ __forceinline__ float rb_(float v) { return __bfloat162float(__float2bfloat16(v)); }

template<bool SECOND>
__global__ __launch_bounds__(256) void conv_bn_naive(
    const void* __restrict__ in_v, const float* __restrict__ wmat,
    const float* __restrict__ g, const float* __restrict__ b,
    const float* __restrict__ rm, const float* __restrict__ rv,
    const float* __restrict__ identity, void* __restrict__ out_v)
{
    constexpr int CI_CHUNK = 8;
    __shared__ float xs[CI_CHUNK][3][58];
    __shared__ float ws_s[4][CI_CHUNK][9];
    const int tid = threadIdx.x;
    const int co_l = tid >> 6;
    const int wl_raw = tid & 63;
    const int wl = wl_raw < (WW - 1) ? wl_raw : (WW - 1);
    const int co = blockIdx.x * 4 + co_l;
    const int h = blockIdx.y, n = blockIdx.z;
    const float* in_f = (const float*)in_v;
    const __hip_bfloat16* in_b = (const __hip_bfloat16*)in_v;
    float acc = 0.f;
    for (int ci0 = 0; ci0 < CC; ci0 += CI_CHUNK) {
        __syncthreads();
        for (int i = tid; i < CI_CHUNK * 3 * 58; i += 256) {
            int ci = i / 174, rem = i - ci * 174, r = rem / 58, col = rem - r * 58;
            int h_in = h + r - 1, x_col = col - 1;
            float v = 0.f;
            if ((unsigned)h_in < HH && (unsigned)x_col < WW) {
                int idx = ((n * CC + ci0 + ci) * HH + h_in) * WW + x_col;
                v = SECOND ? __bfloat162float(in_b[idx]) : rb_(in_f[idx]);
            }
            xs[ci][r][col] = v;
        }
        for (int i = tid; i < 4 * CI_CHUNK * 9; i += 256) {
            int c_l = i / (CI_CHUNK * 9), rem = i - c_l * (CI_CHUNK * 9);
            int ci = rem / 9, k = rem - ci * 9;
            ws_s[c_l][ci][k] = rb_(wmat[(blockIdx.x * 4 + c_l) * CC * 9 + (ci0 + ci) * 9 + k]);
        }
        __syncthreads();
        #pragma unroll
        for (int ci = 0; ci < CI_CHUNK; ++ci) {
            float wr[9];
            #pragma unroll
            for (int k = 0; k < 9; ++k) wr[k] = ws_s[co_l][ci][k];
            #pragma unroll
            for (int dh = 0; dh < 3; ++dh)
                #pragma unroll
                for (int dw = 0; dw < 3; ++dw)
                    acc += xs[ci][dh][wl + dw] * wr[dh * 3 + dw];
        }
    }
    if (wl_raw < WW) {
        float scale = g[co] * rsqrtf(rv[co] + BN_EPS);
        float bias = b[co] - rm[co] * scale;
        float v = acc * scale + bias;
        int oidx = ((n * CC + co) * HH + h) * WW + wl_raw;
        if (SECOND) {
            v += identity[oidx];
            ((float*)out_v)[oidx] = fmaxf(v, 0.f);
        } else {
            ((__hip_bfloat16*)out_v)[oidx] = __float2bfloat16(fmaxf(v, 0.f));
        }
    }
}

// ---------------- launch ----------------
extern "C" void kernel_launch(void* const* d_in, const int* in_sizes, int n_in,
                              void* d_out, int out_size, void* d_ws, size_t ws_size,
                              hipStream_t stream) {
    const float* x   = (const float*)d_in[0];
    const float* w1  = (const float*)d_in[1];
    const float* g1  = (const float*)d_in[2];
    const float* b1  = (const float*)d_in[3];
    const float* rm1 = (const float*)d_in[4];
    const float* rv1 = (const float*)d_in[5];
    const float* w2  = (const float*)d_in[6];
    const float* g2  = (const float*)d_in[7];
    const float* b2  = (const float*)d_in[8];
    const float* rm2 = (const float*)d_in[9];
    const float* rv2 = (const float*)d_in[10];

    const size_t XT_B = (size_t)NN * HP * HP * CC * 2;   // 55,115,776
    const size_t WT_B = (size_t)9 * CC * CC * 2;         // 1,179,648
    const size_t NEED = 2 * XT_B + 2 * WT_B;

    if (ws_size < NEED) {   // safety fallback: round-1 path
        __hip_bfloat16* tmp = (__hip_bfloat16*)d_ws;
        dim3 grid(CC / 4, HH, NN);
        conv_bn_naive<false><<<grid, 256, 0, stream>>>(x, w1, g1, b1, rm1, rv1, nullptr, tmp);
        conv_bn_naive<true ><<<grid, 256, 0, stream>>>(tmp, w2, g2, b2, rm2, rv2, x, d_out);
        return;
    }

    char* ws = (char*)d_ws;
    __hip_bfloat16* xt  = (__hip_bfloat16*)ws;
    __hip_bfloat16* y1  = (__hip_bfloat16*)(ws + XT_B);
    __hip_bfloat16* wt1 = (__hip_bfloat16*)(ws + 2 * XT_B);
    __hip_bfloat16* wt2 = (__hip_bfloat16*)(ws + 2 * XT_B + WT_B);

    zero_borders<<<dim3(228, NN), 256, 0, stream>>>(xt);
    zero_borders<<<dim3(228, NN), 256, 0, stream>>>(y1);
    transform_x <<<dim3(4, HH, NN), 256, 0, stream>>>(x, xt);
    transform_w <<<dim3(CC, 9), 256, 0, stream>>>(w1, wt1);
    transform_w <<<dim3(CC, 9), 256, 0, stream>>>(w2, wt2);

    conv_mfma<false><<<1600, 256, 0, stream>>>(xt, wt1, g1, b1, rm1, rv1, nullptr, y1);
    conv_mfma<true ><<<1600, 256, 0, stream>>>(y1, wt2, g2, b2, rm2, rv2, x, d_out);
}

// Round 5
// 388.651 us; speedup vs baseline: 1.2277x; 1.2277x over previous
//
#include <hip/hip_runtime.h>
#include <hip/hip_bf16.h>

#define NN 32
#define CC 256
#define HH 56
#define WW 56
#define HP 58
#define PIX (HH * WW)          // 3136
#define MTOT (NN * PIX)        // 100352 = 392 * 256
#define BN_EPS 1e-5f

using f32x4  = __attribute__((ext_vector_type(4))) float;
using short8 = __attribute__((ext_vector_type(8))) short;

__device__ __forceinline__ void gload16(const void* g, void* l) {
    __builtin_amdgcn_global_load_lds(
        (const __attribute__((address_space(1))) void*)g,
        (__attribute__((address_space(3))) void*)l, 16, 0, 0);
}

// ---------------- layout transforms ----------------

// x NCHW fp32 -> xt padded NHWC bf16 [N][58][58][256]
__global__ __launch_bounds__(256) void transform_x(const float* __restrict__ x,
                                                   __hip_bfloat16* __restrict__ xt) {
    __shared__ float t[64][65];
    const int tx = threadIdx.x & 63, ty = threadIdx.x >> 6;
    const int c0 = blockIdx.x * 64, h = blockIdx.y, n = blockIdx.z;
    #pragma unroll
    for (int i = 0; i < 16; ++i) {
        const int c = ty + i * 4;
        float v = 0.f;
        if (tx < WW) v = x[(((size_t)n * CC + c0 + c) * HH + h) * WW + tx];
        t[c][tx] = v;
    }
    __syncthreads();
    #pragma unroll
    for (int i = 0; i < 16; ++i) {
        const int w = ty + i * 4;
        if (w < WW)
            xt[((n * HP + h + 1) * HP + (w + 1)) * CC + c0 + tx] = __float2bfloat16(t[tx][w]);
    }
}

// w [co][ci][3][3] fp32 -> wt [tap][co][ci] bf16
__global__ void transform_w(const float* __restrict__ w, __hip_bfloat16* __restrict__ wt) {
    const int co = blockIdx.x, tap = blockIdx.y, ci = threadIdx.x;
    wt[(tap * CC + co) * CC + ci] = __float2bfloat16(w[(co * CC + ci) * 9 + tap]);
}

// zero spatial border of a padded NHWC buffer
__global__ void zero_borders(__hip_bfloat16* __restrict__ buf) {
    const int i = blockIdx.x, n = blockIdx.y;
    int h, w;
    if (i < 58)       { h = 0;              w = i; }
    else if (i < 116) { h = 57;             w = i - 58; }
    else if (i < 172) { h = 1 + (i - 116);  w = 0; }
    else              { h = 1 + (i - 172);  w = 57; }
    buf[((n * HP + h) * HP + w) * CC + threadIdx.x] = __float2bfloat16(0.f);
}

// ---------------- implicit-GEMM conv3x3 + BN (+identity) + ReLU ----------------
// act: padded NHWC bf16 [N][58][58][256]; wt: [9][co=256][ci=256] bf16
// 512 thr = 8 waves (4M x 2N), tile BM=256 global pixels x BN=128 co, BK=64.
// 3-buffer LDS ring, counted vmcnt(12) (T4: loads for t+1,t+2 stay in flight
// across barriers), T2 XOR-swizzle (pre-swizzled source + swizzled ds_read),
// T5 setprio around MFMA. K-order: ci-chunk OUTER, tap INNER (L2-hot re-reads).
template<bool SECOND>
__global__ __launch_bounds__(512) void conv_mfma(
    const __hip_bfloat16* __restrict__ act,
    const __hip_bfloat16* __restrict__ wt,
    const float* __restrict__ g, const float* __restrict__ bb,
    const float* __restrict__ rm, const float* __restrict__ rv,
    const float* __restrict__ identity,
    void* __restrict__ out)
{
    __shared__ short As[3][256 * 64];   // 3 x 32 KB
    __shared__ short Bs[3][128 * 64];   // 3 x 16 KB   (total 144 KB)

    const int tid  = threadIdx.x;
    const int lane = tid & 63;
    const int wid  = tid >> 6;
    const int wm = wid >> 1, wn = wid & 1;

    // XCD swizzle (784 = 8*98, bijective). nb inner: logical pairs share A-tile.
    const int bid     = blockIdx.x;
    const int logical = (bid & 7) * 98 + (bid >> 3);
    const int nb = logical & 1;          // co half
    const int mb = logical >> 1;         // pixel-block 0..391

    // T2: swizzled per-lane source 16B-slot (involution col ^= row&7; row&7 == lane>>3)
    const int scol = (lane & 7) ^ (lane >> 3);

    // Staging bases. Round j covers rows j*64 + wid*8 + (lane>>3).
    int abase[4], bbase[2];
    #pragma unroll
    for (int j = 0; j < 4; ++j) {
        const int r = j * 64 + wid * 8 + (lane >> 3);
        const int p = mb * 256 + r;                 // global pixel, always < MTOT
        const int n   = p / PIX;
        const int rem = p - n * PIX;
        const int h = rem / WW, w = rem - h * WW;
        abase[j] = (((n * HP + h) * HP + w) * CC + scol * 8) * 2;
    }
    #pragma unroll
    for (int j = 0; j < 2; ++j) {
        const int co = nb * 128 + j * 64 + wid * 8 + (lane >> 3);
        bbase[j] = (co * CC + scol * 8) * 2;
    }

    f32x4 acc[4][4];
    #pragma unroll
    for (int i = 0; i < 4; ++i)
        #pragma unroll
        for (int j = 0; j < 4; ++j)
            acc[i][j] = (f32x4){0.f, 0.f, 0.f, 0.f};

    const char* actB = (const char*)act;
    const char* wtB  = (const char*)wt;
    char* AsL = (char*)As;
    char* BsL = (char*)Bs;

    // Stage tile t (cic = t/9, tap = t%9) into ring buffer `buf`. 6 loads/thread.
    auto stage = [&](int buf, int t) {
        const int cic = t / 9;
        const int tap = t - cic * 9;
        const int dh = tap / 3, dw = tap - dh * 3;
        const int aoff = (dh * HP + dw) * (CC * 2) + cic * 128;
        const int boff = tap * (CC * CC * 2) + cic * 128;
        char* Ad = AsL + buf * 32768 + wid * 1024;   // wave-uniform dest (+lane*16 by HW)
        char* Bd = BsL + buf * 16384 + wid * 1024;
        #pragma unroll
        for (int j = 0; j < 4; ++j)
            gload16(actB + abase[j] + aoff, Ad + j * 8192);
        #pragma unroll
        for (int j = 0; j < 2; ++j)
            gload16(wtB + bbase[j] + boff, Bd + j * 8192);
    };

    const int rlane = lane & 15;
    const int xorb  = (rlane & 7) << 4;          // read-side swizzle byte
    const int colb  = (lane >> 4) << 4;

    auto compute = [&](int buf) {
        const char* Ab = AsL + buf * 32768;
        const char* Bb = BsL + buf * 16384;
        __builtin_amdgcn_s_setprio(1);
        #pragma unroll
        for (int ks = 0; ks < 2; ++ks) {
            const int coladdr = (ks * 64 + colb) ^ xorb;
            short8 a[4], bq[4];
            #pragma unroll
            for (int mf = 0; mf < 4; ++mf)
                a[mf] = *(const short8*)(Ab + (wm * 64 + mf * 16 + rlane) * 128 + coladdr);
            #pragma unroll
            for (int nf = 0; nf < 4; ++nf)
                bq[nf] = *(const short8*)(Bb + (wn * 64 + nf * 16 + rlane) * 128 + coladdr);
            #pragma unroll
            for (int mf = 0; mf < 4; ++mf)
                #pragma unroll
                for (int nf = 0; nf < 4; ++nf)
                    acc[mf][nf] = __builtin_amdgcn_mfma_f32_16x16x32_bf16(
                        a[mf], bq[nf], acc[mf][nf], 0, 0, 0);
        }
        __builtin_amdgcn_s_setprio(0);
    };

    // ---- pipeline: 3 tiles in flight, counted vmcnt, never drain to 0 in loop ----
    stage(0, 0); stage(1, 1); stage(2, 2);       // 18 loads/thread outstanding

    #pragma unroll 1
    for (int tt = 0; tt < 33; tt += 3) {         // tt = 0,3,...,30 ; covers t=0..32
        #pragma unroll
        for (int k = 0; k < 3; ++k) {            // buf k == (tt+k)%3
            asm volatile("s_waitcnt vmcnt(12)" ::: "memory");  // tile tt+k ready
            __builtin_amdgcn_s_barrier();
            compute(k);
            __builtin_amdgcn_s_barrier();        // all waves done reading buf k
            stage(k, tt + k + 3);                // stage tile t+3 (<=35)
        }
    }
    // t = 33, 34, 35 tail (outstanding: 34,35 then 35 then none)
    asm volatile("s_waitcnt vmcnt(12)" ::: "memory");
    __builtin_amdgcn_s_barrier();
    compute(0);
    asm volatile("s_waitcnt vmcnt(6)" ::: "memory");
    __builtin_amdgcn_s_barrier();
    compute(1);
    asm volatile("s_waitcnt vmcnt(0)" ::: "memory");
    __builtin_amdgcn_s_barrier();
    compute(2);

    // ---- epilogue: BN (+identity) + ReLU ----
    const int lm = lane >> 4, ln = lane & 15;
    #pragma unroll
    for (int nf = 0; nf < 4; ++nf) {
        const int co = nb * 128 + wn * 64 + nf * 16 + ln;
        const float scale = g[co] * rsqrtf(rv[co] + BN_EPS);
        const float bias  = bb[co] - rm[co] * scale;
        #pragma unroll
        for (int mf = 0; mf < 4; ++mf) {
            const int p0  = mb * 256 + wm * 64 + mf * 16 + lm * 4;  // global pixel, %4==0
            const int n   = p0 / PIX;
            const int pr  = p0 - n * PIX;        // 4 consecutive pixels stay in-image
            f32x4 v = acc[mf][nf];
            if (SECOND) {
                const size_t off = (size_t)(n * CC + co) * PIX + pr;
                const float4 id = *(const float4*)(identity + off);
                float4 o;
                o.x = fmaxf(fmaf(v[0], scale, bias) + id.x, 0.f);
                o.y = fmaxf(fmaf(v[1], scale, bias) + id.y, 0.f);
                o.z = fmaxf(fmaf(v[2], scale, bias) + id.z, 0.f);
                o.w = fmaxf(fmaf(v[3], scale, bias) + id.w, 0.f);
                *(float4*)((float*)out + off) = o;
            } else {
                const int h = pr / WW, w = pr - h * WW;   // same row (56%4==0)
                __hip_bfloat16* yp = (__hip_bfloat16*)out
                    + ((n * HP + h + 1) * HP + (w + 1)) * CC + co;
                #pragma unroll
                for (int r = 0; r < 4; ++r)
                    yp[r * CC] = __float2bfloat16(fmaxf(fmaf(v[r], scale, bias), 0.f));
            }
        }
    }
}

// ---------------- round-1 naive fallback (used only if ws too small) ----------------
__device__ __forceinline__ float rb_(float v) { return __bfloat162float(__float2bfloat16(v)); }

template<bool SECOND>
__global__ __launch_bounds__(256) void conv_bn_naive(
    const void* __restrict__ in_v, const float* __restrict__ wmat,
    const float* __restrict__ g, const float* __restrict__ b,
    const float* __restrict__ rm, const float* __restrict__ rv,
    const float* __restrict__ identity, void* __restrict__ out_v)
{
    constexpr int CI_CHUNK = 8;
    __shared__ float xs[CI_CHUNK][3][58];
    __shared__ float ws_s[4][CI_CHUNK][9];
    const int tid = threadIdx.x;
    const int co_l = tid >> 6;
    const int wl_raw = tid & 63;
    const int wl = wl_raw < (WW - 1) ? wl_raw : (WW - 1);
    const int co = blockIdx.x * 4 + co_l;
    const int h = blockIdx.y, n = blockIdx.z;
    const float* in_f = (const float*)in_v;
    const __hip_bfloat16* in_b = (const __hip_bfloat16*)in_v;
    float acc = 0.f;
    for (int ci0 = 0; ci0 < CC; ci0 += CI_CHUNK) {
        __syncthreads();
        for (int i = tid; i < CI_CHUNK * 3 * 58; i += 256) {
            int ci = i / 174, rem = i - ci * 174, r = rem / 58, col = rem - r * 58;
            int h_in = h + r - 1, x_col = col - 1;
            float v = 0.f;
            if ((unsigned)h_in < HH && (unsigned)x_col < WW) {
                int idx = ((n * CC + ci0 + ci) * HH + h_in) * WW + x_col;
                v = SECOND ? __bfloat162float(in_b[idx]) : rb_(in_f[idx]);
            }
            xs[ci][r][col] = v;
        }
        for (int i = tid; i < 4 * CI_CHUNK * 9; i += 256) {
            int c_l = i / (CI_CHUNK * 9), rem = i - c_l * (CI_CHUNK * 9);
            int ci = rem / 9, k = rem - ci * 9;
            ws_s[c_l][ci][k] = rb_(wmat[(blockIdx.x * 4 + c_l) * CC * 9 + (ci0 + ci) * 9 + k]);
        }
        __syncthreads();
        #pragma unroll
        for (int ci = 0; ci < CI_CHUNK; ++ci) {
            float wr[9];
            #pragma unroll
            for (int k = 0; k < 9; ++k) wr[k] = ws_s[co_l][ci][k];
            #pragma unroll
            for (int dh = 0; dh < 3; ++dh)
                #pragma unroll
                for (int dw = 0; dw < 3; ++dw)
                    acc += xs[ci][dh][wl + dw] * wr[dh * 3 + dw];
        }
    }
    if (wl_raw < WW) {
        float scale = g[co] * rsqrtf(rv[co] + BN_EPS);
        float bias = b[co] - rm[co] * scale;
        float v = acc * scale + bias;
        int oidx = ((n * CC + co) * HH + h) * WW + wl_raw;
        if (SECOND) {
            v += identity[oidx];
            ((float*)out_v)[oidx] = fmaxf(v, 0.f);
        } else {
            ((__hip_bfloat16*)out_v)[oidx] = __float2bfloat16(fmaxf(v, 0.f));
        }
    }
}

// ---------------- launch ----------------
extern "C" void kernel_launch(void* const* d_in, const int* in_sizes, int n_in,
                              void* d_out, int out_size, void* d_ws, size_t ws_size,
                              hipStream_t stream) {
    const float* x   = (const float*)d_in[0];
    const float* w1  = (const float*)d_in[1];
    const float* g1  = (const float*)d_in[2];
    const float* b1  = (const float*)d_in[3];
    const float* rm1 = (const float*)d_in[4];
    const float* rv1 = (const float*)d_in[5];
    const float* w2  = (const float*)d_in[6];
    const float* g2  = (const float*)d_in[7];
    const float* b2  = (const float*)d_in[8];
    const float* rm2 = (const float*)d_in[9];
    const float* rv2 = (const float*)d_in[10];

    const size_t XT_B = (size_t)NN * HP * HP * CC * 2;   // 55,115,776
    const size_t WT_B = (size_t)9 * CC * CC * 2;         // 1,179,648
    const size_t NEED = 2 * XT_B + 2 * WT_B;

    if (ws_size < NEED) {   // safety fallback: round-1 path
        __hip_bfloat16* tmp = (__hip_bfloat16*)d_ws;
        dim3 grid(CC / 4, HH, NN);
        conv_bn_naive<false><<<grid, 256, 0, stream>>>(x, w1, g1, b1, rm1, rv1, nullptr, tmp);
        conv_bn_naive<true ><<<grid, 256, 0, stream>>>(tmp, w2, g2, b2, rm2, rv2, x, d_out);
        return;
    }

    char* ws = (char*)d_ws;
    __hip_bfloat16* xt  = (__hip_bfloat16*)ws;
    __hip_bfloat16* y1  = (__hip_bfloat16*)(ws + XT_B);
    __hip_bfloat16* wt1 = (__hip_bfloat16*)(ws + 2 * XT_B);
    __hip_bfloat16* wt2 = (__hip_bfloat16*)(ws + 2 * XT_B + WT_B);

    zero_borders<<<dim3(228, NN), 256, 0, stream>>>(xt);
    zero_borders<<<dim3(228, NN), 256, 0, stream>>>(y1);
    transform_x <<<dim3(4, HH, NN), 256, 0, stream>>>(x, xt);
    transform_w <<<dim3(CC, 9), 256, 0, stream>>>(w1, wt1);
    transform_w <<<dim3(CC, 9), 256, 0, stream>>>(w2, wt2);

    conv_mfma<false><<<784, 512, 0, stream>>>(xt, wt1, g1, b1, rm1, rv1, nullptr, y1);
    conv_mfma<true ><<<784, 512, 0, stream>>>(y1, wt2, g2, b2, rm2, rv2, x, d_out);
}

// Round 6
// 313.989 us; speedup vs baseline: 1.5197x; 1.2378x over previous
//
#include <hip/hip_runtime.h>
#include <hip/hip_bf16.h>

#define NN 32
#define CC 256
#define HH 56
#define WW 56
#define HP 58
#define PIX (HH * WW)          // 3136
#define MTOT (NN * PIX)        // 100352 = 784 * 128
#define BN_EPS 1e-5f

using f32x4  = __attribute__((ext_vector_type(4))) float;
using short8 = __attribute__((ext_vector_type(8))) short;

__device__ __forceinline__ void gload16(const void* g, void* l) {
    __builtin_amdgcn_global_load_lds(
        (const __attribute__((address_space(1))) void*)g,
        (__attribute__((address_space(3))) void*)l, 16, 0, 0);
}

// ---------------- layout transforms ----------------

// x NCHW fp32 -> xt padded NHWC bf16 [N][58][58][256]
__global__ __launch_bounds__(256) void transform_x(const float* __restrict__ x,
                                                   __hip_bfloat16* __restrict__ xt) {
    __shared__ float t[64][65];
    const int tx = threadIdx.x & 63, ty = threadIdx.x >> 6;
    const int c0 = blockIdx.x * 64, h = blockIdx.y, n = blockIdx.z;
    #pragma unroll
    for (int i = 0; i < 16; ++i) {
        const int c = ty + i * 4;
        float v = 0.f;
        if (tx < WW) v = x[(((size_t)n * CC + c0 + c) * HH + h) * WW + tx];
        t[c][tx] = v;
    }
    __syncthreads();
    #pragma unroll
    for (int i = 0; i < 16; ++i) {
        const int w = ty + i * 4;
        if (w < WW)
            xt[((n * HP + h + 1) * HP + (w + 1)) * CC + c0 + tx] = __float2bfloat16(t[tx][w]);
    }
}

// w [co][ci][3][3] fp32 -> wt [tap][co][ci] bf16
__global__ void transform_w(const float* __restrict__ w, __hip_bfloat16* __restrict__ wt) {
    const int co = blockIdx.x, tap = blockIdx.y, ci = threadIdx.x;
    wt[(tap * CC + co) * CC + ci] = __float2bfloat16(w[(co * CC + ci) * 9 + tap]);
}

// zero spatial border of a padded NHWC buffer
__global__ void zero_borders(__hip_bfloat16* __restrict__ buf) {
    const int i = blockIdx.x, n = blockIdx.y;
    int h, w;
    if (i < 58)       { h = 0;              w = i; }
    else if (i < 116) { h = 57;             w = i - 58; }
    else if (i < 172) { h = 1 + (i - 116);  w = 0; }
    else              { h = 1 + (i - 172);  w = 57; }
    buf[((n * HP + h) * HP + w) * CC + threadIdx.x] = __float2bfloat16(0.f);
}

// ---------------- implicit-GEMM conv3x3 + BN (+identity) + ReLU ----------------
// act: padded NHWC bf16 [N][58][58][256]; wt: [9][co=256][ci=256] bf16
// m97-class structure: 256 thr = 4 waves (2x2), BM=128 pixels x BN=128 co,
// BK=64, SINGLE 32 KB LDS buffer -> 4 blocks/CU co-resident (implicit overlap
// hides the barrier drain, m114). T2 swizzle, T1 XCD swizzle, tap-inner K-order.
template<bool SECOND>
__global__ __launch_bounds__(256, 4) void conv_mfma(
    const __hip_bfloat16* __restrict__ act,
    const __hip_bfloat16* __restrict__ wt,
    const float* __restrict__ g, const float* __restrict__ bb,
    const float* __restrict__ rm, const float* __restrict__ rv,
    const float* __restrict__ identity,
    void* __restrict__ out)
{
    __shared__ short As[128 * 64];   // 16 KB
    __shared__ short Bs[128 * 64];   // 16 KB

    const int tid  = threadIdx.x;
    const int lane = tid & 63;
    const int wid  = tid >> 6;
    const int wm = wid >> 1, wn = wid & 1;

    // T1: bijective XCD swizzle, 1568 = 8 * 196.
    const int bid     = blockIdx.x;
    const int logical = (bid & 7) * 196 + (bid >> 3);
    const int nb = logical & 1;          // co half
    const int mb = logical >> 1;         // pixel-block 0..783

    // T2: swizzled per-lane source 16B-slot (involution col ^= row&7; row == lane>>3 mod 8)
    const int scol = (lane & 7) ^ (lane >> 3);

    // Per-lane staging base byte-offsets. Round j covers rows j*8... wid*32+j*8+(lane>>3).
    int abase[4], bbase[4];
    #pragma unroll
    for (int j = 0; j < 4; ++j) {
        const int r = wid * 32 + j * 8 + (lane >> 3);
        const int p = mb * 128 + r;                // < 100352 always (784*128 exact)
        const int n   = p / PIX;
        const int rem = p - n * PIX;
        const int h = rem / WW, w = rem - h * WW;
        abase[j] = (((n * HP + h) * HP + w) * CC + scol * 8) * 2;
        const int co = nb * 128 + r;
        bbase[j] = (co * CC + scol * 8) * 2;
    }

    f32x4 acc[4][4];
    #pragma unroll
    for (int i = 0; i < 4; ++i)
        #pragma unroll
        for (int j = 0; j < 4; ++j)
            acc[i][j] = (f32x4){0.f, 0.f, 0.f, 0.f};

    const char* actB = (const char*)act;
    const char* wtB  = (const char*)wt;
    char* AsL = (char*)As;
    char* BsL = (char*)Bs;

    const int rlane = lane & 15;
    const int xorb  = (rlane & 7) << 4;          // read-side swizzle byte
    const int colb  = (lane >> 4) << 4;

    // K: ci-chunk OUTER (4 x 64), tap INNER (9) -> tap re-reads are L2 hits.
    for (int cic = 0; cic < 4; ++cic) {
        #pragma unroll
        for (int tap = 0; tap < 9; ++tap) {
            const int dh = tap / 3, dw = tap - dh * 3;
            const int aoff = (dh * HP + dw) * (CC * 2) + cic * 128;
            const int boff = tap * (CC * CC * 2) + cic * 128;
            #pragma unroll
            for (int j = 0; j < 4; ++j) {
                gload16(actB + abase[j] + aoff, AsL + wid * 4096 + j * 1024);
                gload16(wtB  + bbase[j] + boff, BsL + wid * 4096 + j * 1024);
            }
            __syncthreads();                     // drain: tile ready
            __builtin_amdgcn_s_setprio(1);
            #pragma unroll
            for (int ks = 0; ks < 2; ++ks) {
                const int coladdr = (ks * 64 + colb) ^ xorb;
                short8 a[4], bq[4];
                #pragma unroll
                for (int mf = 0; mf < 4; ++mf)
                    a[mf] = *(const short8*)(AsL + (wm * 64 + mf * 16 + rlane) * 128 + coladdr);
                #pragma unroll
                for (int nf = 0; nf < 4; ++nf)
                    bq[nf] = *(const short8*)(BsL + (wn * 64 + nf * 16 + rlane) * 128 + coladdr);
                #pragma unroll
                for (int mf = 0; mf < 4; ++mf)
                    #pragma unroll
                    for (int nf = 0; nf < 4; ++nf)
                        acc[mf][nf] = __builtin_amdgcn_mfma_f32_16x16x32_bf16(
                            a[mf], bq[nf], acc[mf][nf], 0, 0, 0);
            }
            __builtin_amdgcn_s_setprio(0);
            __syncthreads();                     // all waves done reading before overwrite
        }
    }

    // ---- epilogue: BN (+identity) + ReLU ----
    const int lm = lane >> 4, ln = lane & 15;
    #pragma unroll
    for (int nf = 0; nf < 4; ++nf) {
        const int co = nb * 128 + wn * 64 + nf * 16 + ln;
        const float scale = g[co] * rsqrtf(rv[co] + BN_EPS);
        const float bias  = bb[co] - rm[co] * scale;
        #pragma unroll
        for (int mf = 0; mf < 4; ++mf) {
            const int p0  = mb * 128 + wm * 64 + mf * 16 + lm * 4;  // global pixel, %4==0
            const int n   = p0 / PIX;
            const int pr  = p0 - n * PIX;        // 4 consecutive pixels stay in row/image
            f32x4 v = acc[mf][nf];
            if (SECOND) {
                const size_t off = (size_t)(n * CC + co) * PIX + pr;
                const float4 id = *(const float4*)(identity + off);
                float4 o;
                o.x = fmaxf(fmaf(v[0], scale, bias) + id.x, 0.f);
                o.y = fmaxf(fmaf(v[1], scale, bias) + id.y, 0.f);
                o.z = fmaxf(fmaf(v[2], scale, bias) + id.z, 0.f);
                o.w = fmaxf(fmaf(v[3], scale, bias) + id.w, 0.f);
                *(float4*)((float*)out + off) = o;
            } else {
                const int h = pr / WW, w = pr - h * WW;   // same row (56%4==0)
                __hip_bfloat16* yp = (__hip_bfloat16*)out
                    + ((n * HP + h + 1) * HP + (w + 1)) * CC + co;
                #pragma unroll
                for (int r = 0; r < 4; ++r)
                    yp[r * CC] = __float2bfloat16(fmaxf(fmaf(v[r], scale, bias), 0.f));
            }
        }
    }
}

// ---------------- round-1 naive fallback (used only if ws too small) ----------------
__device__ __forceinline__ float rb_(float v) { return __bfloat162float(__float2bfloat16(v)); }

template<bool SECOND>
__global__ __launch_bounds__(256) void conv_bn_naive(
    const void* __restrict__ in_v, const float* __restrict__ wmat,
    const float* __restrict__ g, const float* __restrict__ b,
    const float* __restrict__ rm, const float* __restrict__ rv,
    const float* __restrict__ identity, void* __restrict__ out_v)
{
    constexpr int CI_CHUNK = 8;
    __shared__ float xs[CI_CHUNK][3][58];
    __shared__ float ws_s[4][CI_CHUNK][9];
    const int tid = threadIdx.x;
    const int co_l = tid >> 6;
    const int wl_raw = tid & 63;
    const int wl = wl_raw < (WW - 1) ? wl_raw : (WW - 1);
    const int co = blockIdx.x * 4 + co_l;
    const int h = blockIdx.y, n = blockIdx.z;
    const float* in_f = (const float*)in_v;
    const __hip_bfloat16* in_b = (const __hip_bfloat16*)in_v;
    float acc = 0.f;
    for (int ci0 = 0; ci0 < CC; ci0 += CI_CHUNK) {
        __syncthreads();
        for (int i = tid; i < CI_CHUNK * 3 * 58; i += 256) {
            int ci = i / 174, rem = i - ci * 174, r = rem / 58, col = rem - r * 58;
            int h_in = h + r - 1, x_col = col - 1;
            float v = 0.f;
            if ((unsigned)h_in < HH && (unsigned)x_col < WW) {
                int idx = ((n * CC + ci0 + ci) * HH + h_in) * WW + x_col;
                v = SECOND ? __bfloat162float(in_b[idx]) : rb_(in_f[idx]);
            }
            xs[ci][r][col] = v;
        }
        for (int i = tid; i < 4 * CI_CHUNK * 9; i += 256) {
            int c_l = i / (CI_CHUNK * 9), rem = i - c_l * (CI_CHUNK * 9);
            int ci = rem / 9, k = rem - ci * 9;
            ws_s[c_l][ci][k] = rb_(wmat[(blockIdx.x * 4 + c_l) * CC * 9 + (ci0 + ci) * 9 + k]);
        }
        __syncthreads();
        #pragma unroll
        for (int ci = 0; ci < CI_CHUNK; ++ci) {
            float wr[9];
            #pragma unroll
            for (int k = 0; k < 9; ++k) wr[k] = ws_s[co_l][ci][k];
            #pragma unroll
            for (int dh = 0; dh < 3; ++dh)
                #pragma unroll
                for (int dw = 0; dw < 3; ++dw)
                    acc += xs[ci][dh][wl + dw] * wr[dh * 3 + dw];
        }
    }
    if (wl_raw < WW) {
        float scale = g[co] * rsqrtf(rv[co] + BN_EPS);
        float bias = b[co] - rm[co] * scale;
        float v = acc * scale + bias;
        int oidx = ((n * CC + co) * HH + h) * WW + wl_raw;
        if (SECOND) {
            v += identity[oidx];
            ((float*)out_v)[oidx] = fmaxf(v, 0.f);
        } else {
            ((__hip_bfloat16*)out_v)[oidx] = __float2bfloat16(fmaxf(v, 0.f));
        }
    }
}

// ---------------- launch ----------------
extern "C" void kernel_launch(void* const* d_in, const int* in_sizes, int n_in,
                              void* d_out, int out_size, void* d_ws, size_t ws_size,
                              hipStream_t stream) {
    const float* x   = (const float*)d_in[0];
    const float* w1  = (const float*)d_in[1];
    const float* g1  = (const float*)d_in[2];
    const float* b1  = (const float*)d_in[3];
    const float* rm1 = (const float*)d_in[4];
    const float* rv1 = (const float*)d_in[5];
    const float* w2  = (const float*)d_in[6];
    const float* g2  = (const float*)d_in[7];
    const float* b2  = (const float*)d_in[8];
    const float* rm2 = (const float*)d_in[9];
    const float* rv2 = (const float*)d_in[10];

    const size_t XT_B = (size_t)NN * HP * HP * CC * 2;   // 55,115,776
    const size_t WT_B = (size_t)9 * CC * CC * 2;         // 1,179,648
    const size_t NEED = 2 * XT_B + 2 * WT_B;

    if (ws_size < NEED) {   // safety fallback: round-1 path
        __hip_bfloat16* tmp = (__hip_bfloat16*)d_ws;
        dim3 grid(CC / 4, HH, NN);
        conv_bn_naive<false><<<grid, 256, 0, stream>>>(x, w1, g1, b1, rm1, rv1, nullptr, tmp);
        conv_bn_naive<true ><<<grid, 256, 0, stream>>>(tmp, w2, g2, b2, rm2, rv2, x, d_out);
        return;
    }

    char* ws = (char*)d_ws;
    __hip_bfloat16* xt  = (__hip_bfloat16*)ws;
    __hip_bfloat16* y1  = (__hip_bfloat16*)(ws + XT_B);
    __hip_bfloat16* wt1 = (__hip_bfloat16*)(ws + 2 * XT_B);
    __hip_bfloat16* wt2 = (__hip_bfloat16*)(ws + 2 * XT_B + WT_B);

    zero_borders<<<dim3(228, NN), 256, 0, stream>>>(xt);
    zero_borders<<<dim3(228, NN), 256, 0, stream>>>(y1);
    transform_x <<<dim3(4, HH, NN), 256, 0, stream>>>(x, xt);
    transform_w <<<dim3(CC, 9), 256, 0, stream>>>(w1, wt1);
    transform_w <<<dim3(CC, 9), 256, 0, stream>>>(w2, wt2);

    conv_mfma<false><<<1568, 256, 0, stream>>>(xt, wt1, g1, b1, rm1, rv1, nullptr, y1);
    conv_mfma<true ><<<1568, 256, 0, stream>>>(y1, wt2, g2, b2, rm2, rv2, x, d_out);
}